// Round 14
// baseline (297.810 us; speedup 1.0000x reference)
//
#include <hip/hip_runtime.h>
#include <hip/hip_fp16.h>

#define NEG_SLOPE 0.2f

constexpr int IN_F = 256;   // input feature dim
constexpr int NT   = 8;     // edge types
constexpr int NH   = 16;    // heads
constexpr int ND   = 16;    // head dim
constexpr int TM   = 32;    // nodes per proj block

constexpr int NPB_SHIFT = 7;
constexpr int NPB    = 128;   // nodes per bucket (pow2)
constexpr int MAX_NB = 1024;  // supports N <= 131072
constexpr int CAP    = 4736;  // LDS edge capacity per sum chunk
constexpr int CAPB   = 6144;  // arena slots per bucket (mean 4096, +32 sigma)
constexpr int SCH    = 3200;  // scatter chunk size (ushort-indexable)

// ---------------------------------------------------------------------------
// Kernel A: pre-contract weights with attn sums, packed for the proj kernel.
// ---------------------------------------------------------------------------
__global__ void precompute_w_kernel(const float* __restrict__ W,
                                    const float* __restrict__ attn_l,
                                    const float* __restrict__ attn_r,
                                    float4* __restrict__ Wc) {
    int t = blockIdx.x;
    __shared__ float alsum[NH];
    __shared__ float arsum[NH];
    int tid = threadIdx.x;
    if (tid < NH) {
        float a = 0.f, b = 0.f;
        for (int k = 0; k < ND; ++k) {
            a += attn_l[(t * NH + tid) * ND + k];
            b += attn_r[(t * NH + tid) * ND + k];
        }
        alsum[tid] = a;
        arsum[tid] = b;
    }
    __syncthreads();
    int i = tid;  // 0..255
    const float* wrow = W + ((size_t)t * IN_F + i) * (NH * ND);
    float sl[NH], sr[NH];
    for (int h = 0; h < NH; ++h) {
        float a = 0.f, b = 0.f;
        for (int j = 0; j < ND; ++j) {
            float w = wrow[h * ND + j];
            a += w * alsum[j];
            b += w * arsum[j];
        }
        sl[h] = a;
        sr[h] = b;
    }
    float4* dst = Wc + ((size_t)t * IN_F + i) * 8;
    for (int q = 0; q < 8; ++q) {
        float4 v;
        v.x = sl[q]; v.y = sl[q + 8]; v.z = sr[q]; v.w = sr[q + 8];
        dst[q] = v;
    }
}

// ---------------------------------------------------------------------------
// Kernel B: per-node projections, WEIGHTS staged in LDS (32 KB), x streamed
// as float4. etype is sorted -> type-uniform blocks (mixed-block fallback).
// el stored FP16 (3.2 MB, L2-resident for gathers); er fp32 (coalesced).
// ---------------------------------------------------------------------------
__global__ __launch_bounds__(256) void node_proj_kernel(
        const float* __restrict__ x,
        const int* __restrict__ etype,
        const float4* __restrict__ Wc,
        __half* __restrict__ elh,
        float* __restrict__ er,
        int N) {
    __shared__ float4 wt[IN_F * 8];  // 32 KB
    __shared__ int s_uni;
    __shared__ int s_t0;
    int tid = threadIdx.x;
    int n0 = blockIdx.x * TM;
    if (tid == 0) { s_t0 = etype[n0]; s_uni = 1; }
    __syncthreads();
    if (tid < TM) {
        int nn = n0 + tid;
        if (nn < N && etype[nn] != s_t0) s_uni = 0;  // benign race: all write 0
    }
    __syncthreads();

    int nl = tid >> 3, q = tid & 7;
    int n = n0 + nl;
    float al0 = 0.f, al1 = 0.f, ar0 = 0.f, ar1 = 0.f;

    if (s_uni) {
        const float4* wsrc = Wc + (size_t)s_t0 * IN_F * 8;
        #pragma unroll
        for (int j = 0; j < 8; ++j) wt[j * 256 + tid] = wsrc[j * 256 + tid];
        __syncthreads();
        if (n >= N) return;
        const float4* xp4 = (const float4*)(x + (size_t)n * IN_F);
        #pragma unroll 2
        for (int i4 = 0; i4 < IN_F / 4; ++i4) {
            float4 xv = xp4[i4];
            float4 w0 = wt[(i4 * 4 + 0) * 8 + q];
            float4 w1 = wt[(i4 * 4 + 1) * 8 + q];
            float4 w2 = wt[(i4 * 4 + 2) * 8 + q];
            float4 w3 = wt[(i4 * 4 + 3) * 8 + q];
            al0 += xv.x * w0.x; al1 += xv.x * w0.y; ar0 += xv.x * w0.z; ar1 += xv.x * w0.w;
            al0 += xv.y * w1.x; al1 += xv.y * w1.y; ar0 += xv.y * w1.z; ar1 += xv.y * w1.w;
            al0 += xv.z * w2.x; al1 += xv.z * w2.y; ar0 += xv.z * w2.z; ar1 += xv.z * w2.w;
            al0 += xv.w * w3.x; al1 += xv.w * w3.y; ar0 += xv.w * w3.z; ar1 += xv.w * w3.w;
        }
    } else {
        if (n >= N) return;
        int t = etype[n];
        const float4* wc = Wc + (size_t)t * IN_F * 8 + q;
        const float4* xp4 = (const float4*)(x + (size_t)n * IN_F);
        #pragma unroll 2
        for (int i4 = 0; i4 < IN_F / 4; ++i4) {
            float4 xv = xp4[i4];
            float4 w0 = wc[(size_t)(i4 * 4 + 0) * 8];
            float4 w1 = wc[(size_t)(i4 * 4 + 1) * 8];
            float4 w2 = wc[(size_t)(i4 * 4 + 2) * 8];
            float4 w3 = wc[(size_t)(i4 * 4 + 3) * 8];
            al0 += xv.x * w0.x; al1 += xv.x * w0.y; ar0 += xv.x * w0.z; ar1 += xv.x * w0.w;
            al0 += xv.y * w1.x; al1 += xv.y * w1.y; ar0 += xv.y * w1.z; ar1 += xv.y * w1.w;
            al0 += xv.z * w2.x; al1 += xv.z * w2.y; ar0 += xv.z * w2.z; ar1 += xv.z * w2.w;
            al0 += xv.w * w3.x; al1 += xv.w * w3.y; ar0 += xv.w * w3.z; ar1 += xv.w * w3.w;
        }
    }
    elh[(size_t)n * NH + q]     = __float2half(al0);
    elh[(size_t)n * NH + q + 8] = __float2half(al1);
    er[(size_t)n * NH + q]      = ar0;
    er[(size_t)n * NH + q + 8]  = ar1;
}

// ---------------------------------------------------------------------------
// Kernel C: scatter with per-bucket arena reservation + in-LDS sort.
// Grid = ceil(E/SCH) blocks x 512 threads (chunk 3200 -> ~31 waves/CU;
// round-13 ran 512 blocks = 16 waves/CU, concurrency-starved).
// ---------------------------------------------------------------------------
__global__ __launch_bounds__(512) void scatter_reserve_kernel(
        const int* __restrict__ dst,
        const int* __restrict__ src,
        int* __restrict__ cursor,        // [NB], zeroed before launch
        uint2* __restrict__ packed,      // [NB * CAPB] arenas
        int E, int NB) {
    __shared__ unsigned short sidx[SCH];   // 6.4 KB
    __shared__ int hist[MAX_NB];           // counts -> reset -> running cur
    __shared__ int start_[MAX_NB];         // in-chunk exclusive starts
    __shared__ int base_[MAX_NB];          // arena reservations
    __shared__ int wsc[8];
    int tid = threadIdx.x;
    int chunk = (E + gridDim.x - 1) / gridDim.x;   // <= SCH by grid sizing
    int e0 = blockIdx.x * chunk;
    int e1 = min(E, e0 + chunk);
    int cc = e1 - e0;
    if (cc <= 0) return;

    for (int i = tid; i < MAX_NB; i += 512) hist[i] = 0;
    __syncthreads();
    for (int i = tid; i < cc; i += 512)
        atomicAdd(&hist[dst[e0 + i] >> NPB_SHIFT], 1);
    __syncthreads();
    for (int b = tid; b < NB; b += 512) {
        int c = hist[b];
        base_[b] = (c > 0) ? atomicAdd(&cursor[b], c) : 0;
    }
    int i0 = tid * 2;
    int c0 = hist[i0], c1 = hist[i0 + 1];
    int s2 = c0 + c1;
    int lane = tid & 63, wv = tid >> 6;
    int v = s2;
    #pragma unroll
    for (int off = 1; off < 64; off <<= 1) {
        int u = __shfl_up(v, (unsigned)off);
        v += (lane >= off) ? u : 0;
    }
    if (lane == 63) wsc[wv] = v;
    __syncthreads();
    int woff = 0;
    #pragma unroll
    for (int q = 0; q < 8; ++q) woff += (q < wv) ? wsc[q] : 0;
    int excl = woff + v - s2;
    start_[i0]     = excl;
    start_[i0 + 1] = excl + c0;
    for (int i = tid; i < MAX_NB; i += 512) hist[i] = 0;
    __syncthreads();
    for (int i = tid; i < cc; i += 512) {
        int b = dst[e0 + i] >> NPB_SHIFT;
        int lp = atomicAdd(&hist[b], 1);
        sidx[start_[b] + lp] = (unsigned short)i;
    }
    __syncthreads();
    for (int i = tid; i < cc; i += 512) {
        int le = sidx[i];
        int e = e0 + le;
        int d = dst[e];                    // L1/L2-hot gather (chunk slice)
        int b = d >> NPB_SHIFT;
        int dp = base_[b] + (i - start_[b]);
        if (dp < CAPB) {  // overflow guard (P ~ 1e-20 at CAPB = mean+32sigma)
            unsigned lo = ((unsigned)src[e] << NPB_SHIFT) | (unsigned)(d & (NPB - 1));
            unsigned long long v64 = ((unsigned long long)(unsigned)e << 32) |
                                     (unsigned long long)lo;
            __builtin_nontemporal_store(
                v64, (unsigned long long*)&packed[(size_t)b * CAPB + dp]);
        }
    }
}

// ---------------------------------------------------------------------------
// Kernel D: FUSED per-bucket softmax + output write, HALF2-PACKED.
//   Lane = k*8 + hp: each lane handles head pair (2hp, 2hp+1) via one
//   __half2 gather -> halves gathers (25.6M, 32B/edge), srt broadcasts,
//   address math; 8 edges in flight per wave (2x MLP). Phase-2 emits one
//   8B NT store per lane (8 lanes = 64B/edge run). Reduce = shfl_xor over
//   {8,16,32} (the k bits), full-wave uniform.
// ---------------------------------------------------------------------------
__global__ __launch_bounds__(512) void bucket_sum_kernel(
        const uint2* __restrict__ packed,
        const int* __restrict__ cursor,
        const __half* __restrict__ elh,
        const float* __restrict__ er,
        float* __restrict__ out,
        int N) {
    __shared__ unsigned srt[CAP];         // 18.9 KB (src<<7 | dl)
    __shared__ int cnt0[NPB];
    __shared__ int csum[NPB];
    __shared__ int cur[NPB];
    __shared__ float2 erbuf2[NPB * 9];    // 9.2 KB, padded (stride 9)
    __shared__ float2 invbuf2[NPB * 9];   // 9.2 KB, padded
    int b = blockIdx.x;
    int base = b << NPB_SHIFT;
    size_t off = (size_t)b * CAPB;
    int tid = threadIdx.x;
    int lane = tid & 63;
    int w = tid >> 6;          // wave 0..7
    int hp = lane & 7;         // head pair: heads 2hp, 2hp+1
    int k = lane >> 3;         // edge group 0..7
    int cntb = min(cursor[b], CAPB);
    int nvalid = min(NPB, N - base);

    // stage er as float2 pairs (coalesced)
    for (int s = tid; s < nvalid * 8; s += 512) {
        int dl = s >> 3, hh = s & 7;
        erbuf2[dl * 9 + hh] = *(const float2*)&er[(size_t)(base + dl) * NH + 2 * hh];
    }

    float2 sacc[16];
    #pragma unroll
    for (int nn = 0; nn < 16; ++nn) { sacc[nn].x = 0.f; sacc[nn].y = 0.f; }

    int nchunks = (cntb + CAP - 1) / CAP;

    // ---- Phase 1: chunked counting sort + register sums ----
    for (int c = 0; c < nchunks; ++c) {
        int cbase = c * CAP;
        int cc = min(CAP, cntb - cbase);
        for (int i = tid; i < NPB; i += 512) { cnt0[i] = 0; cur[i] = 0; }
        __syncthreads();
        for (int i = tid; i < cc; i += 512)
            atomicAdd(&cnt0[packed[off + cbase + i].x & (NPB - 1)], 1);
        __syncthreads();
        // single-wave inclusive scan of 128 bins (wave 0, 2 bins/lane)
        if (w == 0) {
            int a  = cnt0[lane];
            int bb = cnt0[64 + lane];
            int va = a, vb = bb;
            #pragma unroll
            for (int offs = 1; offs < 64; offs <<= 1) {
                int ua = __shfl_up(va, (unsigned)offs);
                int ub = __shfl_up(vb, (unsigned)offs);
                va += (lane >= offs) ? ua : 0;
                vb += (lane >= offs) ? ub : 0;
            }
            int totA = __shfl(va, 63);
            csum[lane]      = va;
            csum[64 + lane] = vb + totA;
        }
        __syncthreads();
        for (int i = tid; i < cc; i += 512) {
            unsigned px = packed[off + cbase + i].x;
            int dl = (int)(px & (NPB - 1));
            int lp = atomicAdd(&cur[dl], 1);
            srt[csum[dl] - cnt0[dl] + lp] = px;
        }
        __syncthreads();
        // wave-per-node register sums: 8 edge groups, 2-way ILP, half2 math
        #pragma unroll
        for (int nn = 0; nn < 16; ++nn) {
            int dl = w * 16 + nn;
            int m = cnt0[dl];        // wave-uniform
            if (m == 0) continue;
            int offL = csum[dl] - m;
            float2 er2 = erbuf2[dl * 9 + hp];
            float s0x = 0.f, s0y = 0.f, s1x = 0.f, s1y = 0.f;
            int j = k;
            for (; j + 8 < m; j += 16) {
                unsigned p0 = srt[offL + j];
                unsigned p1 = srt[offL + j + 8];
                float2 f0 = __half22float2(
                    *(const __half2*)&elh[(size_t)(p0 >> NPB_SHIFT) * NH + 2 * hp]);
                float2 f1 = __half22float2(
                    *(const __half2*)&elh[(size_t)(p1 >> NPB_SHIFT) * NH + 2 * hp]);
                float v0x = f0.x + er2.x, v0y = f0.y + er2.y;
                float v1x = f1.x + er2.x, v1y = f1.y + er2.y;
                v0x = v0x > 0.f ? v0x : NEG_SLOPE * v0x;
                v0y = v0y > 0.f ? v0y : NEG_SLOPE * v0y;
                v1x = v1x > 0.f ? v1x : NEG_SLOPE * v1x;
                v1y = v1y > 0.f ? v1y : NEG_SLOPE * v1y;
                s0x += __expf(v0x); s0y += __expf(v0y);
                s1x += __expf(v1x); s1y += __expf(v1y);
            }
            if (j < m) {
                unsigned p0 = srt[offL + j];
                float2 f0 = __half22float2(
                    *(const __half2*)&elh[(size_t)(p0 >> NPB_SHIFT) * NH + 2 * hp]);
                float v0x = f0.x + er2.x, v0y = f0.y + er2.y;
                v0x = v0x > 0.f ? v0x : NEG_SLOPE * v0x;
                v0y = v0y > 0.f ? v0y : NEG_SLOPE * v0y;
                s0x += __expf(v0x); s0y += __expf(v0y);
            }
            sacc[nn].x += s0x + s1x;
            sacc[nn].y += s0y + s1y;
        }
        if (c + 1 < nchunks) __syncthreads();
    }

    // ---- reduce sacc over k groups (lane bits 3..5), full-wave uniform ----
    #pragma unroll
    for (int nn = 0; nn < 16; ++nn) {
        int dl = w * 16 + nn;
        float sx = sacc[nn].x, sy = sacc[nn].y;
        sx += __shfl_xor(sx, 8);  sy += __shfl_xor(sy, 8);
        sx += __shfl_xor(sx, 16); sy += __shfl_xor(sy, 16);
        sx += __shfl_xor(sx, 32); sy += __shfl_xor(sy, 32);
        if (k == 0) {
            float2 iv; iv.x = 1.0f / sx; iv.y = 1.0f / sy;  // inf for deg-0: never read
            invbuf2[dl * 9 + hp] = iv;
        }
    }
    __syncthreads();

    // ---- Phase 2: normalized outputs, half2 + 8B NT stores, 2-way ILP ----
    int i = (tid >> 3);
    for (; i + 64 < cntb; i += 128) {
        uint2 p0 = packed[off + i];
        uint2 p1 = packed[off + i + 64];
        int dl0 = (int)(p0.x & (NPB - 1)), dl1 = (int)(p1.x & (NPB - 1));
        float2 f0 = __half22float2(
            *(const __half2*)&elh[(size_t)(p0.x >> NPB_SHIFT) * NH + 2 * hp]);
        float2 f1 = __half22float2(
            *(const __half2*)&elh[(size_t)(p1.x >> NPB_SHIFT) * NH + 2 * hp]);
        float2 e0 = erbuf2[dl0 * 9 + hp], e1 = erbuf2[dl1 * 9 + hp];
        float2 i0 = invbuf2[dl0 * 9 + hp], i1 = invbuf2[dl1 * 9 + hp];
        float v0x = f0.x + e0.x, v0y = f0.y + e0.y;
        float v1x = f1.x + e1.x, v1y = f1.y + e1.y;
        v0x = v0x > 0.f ? v0x : NEG_SLOPE * v0x;
        v0y = v0y > 0.f ? v0y : NEG_SLOPE * v0y;
        v1x = v1x > 0.f ? v1x : NEG_SLOPE * v1x;
        v1y = v1y > 0.f ? v1y : NEG_SLOPE * v1y;
        union { float f[2]; unsigned long long u; } pk0, pk1;
        pk0.f[0] = __expf(v0x) * i0.x; pk0.f[1] = __expf(v0y) * i0.y;
        pk1.f[0] = __expf(v1x) * i1.x; pk1.f[1] = __expf(v1y) * i1.y;
        __builtin_nontemporal_store(
            pk0.u, (unsigned long long*)&out[(size_t)p0.y * NH + 2 * hp]);
        __builtin_nontemporal_store(
            pk1.u, (unsigned long long*)&out[(size_t)p1.y * NH + 2 * hp]);
    }
    if (i < cntb) {
        uint2 p0 = packed[off + i];
        int dl0 = (int)(p0.x & (NPB - 1));
        float2 f0 = __half22float2(
            *(const __half2*)&elh[(size_t)(p0.x >> NPB_SHIFT) * NH + 2 * hp]);
        float2 e0 = erbuf2[dl0 * 9 + hp];
        float2 i0 = invbuf2[dl0 * 9 + hp];
        float v0x = f0.x + e0.x, v0y = f0.y + e0.y;
        v0x = v0x > 0.f ? v0x : NEG_SLOPE * v0x;
        v0y = v0y > 0.f ? v0y : NEG_SLOPE * v0y;
        union { float f[2]; unsigned long long u; } pk0;
        pk0.f[0] = __expf(v0x) * i0.x; pk0.f[1] = __expf(v0y) * i0.y;
        __builtin_nontemporal_store(
            pk0.u, (unsigned long long*)&out[(size_t)p0.y * NH + 2 * hp]);
    }
}

extern "C" void kernel_launch(void* const* d_in, const int* in_sizes, int n_in,
                              void* d_out, int out_size, void* d_ws, size_t ws_size,
                              hipStream_t stream) {
    const float* x      = (const float*)d_in[0];  // [N, 256]
    const float* W      = (const float*)d_in[1];  // [8, 256, 256]
    const float* attn_l = (const float*)d_in[2];  // [8, 16, 16]
    const float* attn_r = (const float*)d_in[3];  // [8, 16, 16]
    const int*   etype  = (const int*)d_in[4];    // [N]
    const int*   src    = (const int*)d_in[5];    // [E]
    const int*   dst    = (const int*)d_in[6];    // [E]

    int N = in_sizes[4];
    int E = in_sizes[5];
    int NB = (N + NPB - 1) >> NPB_SHIFT;  // 782 for N=100000

    float* out = (float*)d_out;  // [E, 16]

    // Workspace layout (~48 MB total, aligned chunks).
    char* ws = (char*)d_ws;
    float4* Wc     = (float4*)ws;                              // 256 KB
    __half* elh    = (__half*)(Wc + (size_t)NT * IN_F * 8);    // N*16 halfs
    float*  er     = (float*)(elh + (size_t)N * NH);           // N*16 floats
    int*    cursor = (int*)(er + (size_t)N * NH);              // MAX_NB ints
    uint2*  packed = (uint2*)(cursor + MAX_NB);                // NB*CAPB uint2

    hipMemsetAsync(cursor, 0, (size_t)NB * sizeof(int), stream);

    precompute_w_kernel<<<NT, 256, 0, stream>>>(W, attn_l, attn_r, Wc);

    int nb_proj = (N + TM - 1) / TM;
    node_proj_kernel<<<nb_proj, 256, 0, stream>>>(x, etype, Wc, elh, er, N);

    int nblk_s = (E + SCH - 1) / SCH;   // 1000 for E=3.2M
    scatter_reserve_kernel<<<nblk_s, 512, 0, stream>>>(dst, src, cursor, packed, E, NB);

    bucket_sum_kernel<<<NB, 512, 0, stream>>>(packed, cursor, elh, er, out, N);
}

// Round 15
// 215.134 us; speedup vs baseline: 1.3843x; 1.3843x over previous
//
#include <hip/hip_runtime.h>
#include <hip/hip_fp16.h>

#define NEG_SLOPE 0.2f

constexpr int IN_F = 256;   // input feature dim
constexpr int NT   = 8;     // edge types
constexpr int NH   = 16;    // heads
constexpr int ND   = 16;    // head dim
constexpr int TM   = 32;    // nodes per proj block

constexpr int NPB_SHIFT = 7;
constexpr int NPB    = 128;   // nodes per bucket (pow2)
constexpr int MAX_NB = 1024;  // supports N <= 131072
constexpr int CAP    = 4736;  // LDS edge capacity per sum chunk
constexpr int CAPB   = 6144;  // arena slots per bucket (mean 4096, +32 sigma)
constexpr int NBLK_S = 512;   // blocks for scatter_reserve (512 threads each)
constexpr int SCH    = 6272;  // max chunk = ceil(3.2M/512) = 6250, rounded up

// ---------------------------------------------------------------------------
// Kernel A: pre-contract weights with attn sums, packed for the proj kernel.
// ---------------------------------------------------------------------------
__global__ void precompute_w_kernel(const float* __restrict__ W,
                                    const float* __restrict__ attn_l,
                                    const float* __restrict__ attn_r,
                                    float4* __restrict__ Wc) {
    int t = blockIdx.x;
    __shared__ float alsum[NH];
    __shared__ float arsum[NH];
    int tid = threadIdx.x;
    if (tid < NH) {
        float a = 0.f, b = 0.f;
        for (int k = 0; k < ND; ++k) {
            a += attn_l[(t * NH + tid) * ND + k];
            b += attn_r[(t * NH + tid) * ND + k];
        }
        alsum[tid] = a;
        arsum[tid] = b;
    }
    __syncthreads();
    int i = tid;  // 0..255
    const float* wrow = W + ((size_t)t * IN_F + i) * (NH * ND);
    float sl[NH], sr[NH];
    for (int h = 0; h < NH; ++h) {
        float a = 0.f, b = 0.f;
        for (int j = 0; j < ND; ++j) {
            float w = wrow[h * ND + j];
            a += w * alsum[j];
            b += w * arsum[j];
        }
        sl[h] = a;
        sr[h] = b;
    }
    float4* dst = Wc + ((size_t)t * IN_F + i) * 8;
    for (int q = 0; q < 8; ++q) {
        float4 v;
        v.x = sl[q]; v.y = sl[q + 8]; v.z = sr[q]; v.w = sr[q + 8];
        dst[q] = v;
    }
}

// ---------------------------------------------------------------------------
// Kernel B: per-node projections, WEIGHTS staged in LDS (32 KB), x streamed
// as float4. etype is sorted -> type-uniform blocks (mixed-block fallback).
// el stored FP16 (3.2 MB, L2-resident for gathers); er fp32 (coalesced).
// ---------------------------------------------------------------------------
__global__ __launch_bounds__(256) void node_proj_kernel(
        const float* __restrict__ x,
        const int* __restrict__ etype,
        const float4* __restrict__ Wc,
        __half* __restrict__ elh,
        float* __restrict__ er,
        int N) {
    __shared__ float4 wt[IN_F * 8];  // 32 KB
    __shared__ int s_uni;
    __shared__ int s_t0;
    int tid = threadIdx.x;
    int n0 = blockIdx.x * TM;
    if (tid == 0) { s_t0 = etype[n0]; s_uni = 1; }
    __syncthreads();
    if (tid < TM) {
        int nn = n0 + tid;
        if (nn < N && etype[nn] != s_t0) s_uni = 0;  // benign race: all write 0
    }
    __syncthreads();

    int nl = tid >> 3, q = tid & 7;
    int n = n0 + nl;
    float al0 = 0.f, al1 = 0.f, ar0 = 0.f, ar1 = 0.f;

    if (s_uni) {
        const float4* wsrc = Wc + (size_t)s_t0 * IN_F * 8;
        #pragma unroll
        for (int j = 0; j < 8; ++j) wt[j * 256 + tid] = wsrc[j * 256 + tid];
        __syncthreads();
        if (n >= N) return;
        const float4* xp4 = (const float4*)(x + (size_t)n * IN_F);
        #pragma unroll 2
        for (int i4 = 0; i4 < IN_F / 4; ++i4) {
            float4 xv = xp4[i4];
            float4 w0 = wt[(i4 * 4 + 0) * 8 + q];
            float4 w1 = wt[(i4 * 4 + 1) * 8 + q];
            float4 w2 = wt[(i4 * 4 + 2) * 8 + q];
            float4 w3 = wt[(i4 * 4 + 3) * 8 + q];
            al0 += xv.x * w0.x; al1 += xv.x * w0.y; ar0 += xv.x * w0.z; ar1 += xv.x * w0.w;
            al0 += xv.y * w1.x; al1 += xv.y * w1.y; ar0 += xv.y * w1.z; ar1 += xv.y * w1.w;
            al0 += xv.z * w2.x; al1 += xv.z * w2.y; ar0 += xv.z * w2.z; ar1 += xv.z * w2.w;
            al0 += xv.w * w3.x; al1 += xv.w * w3.y; ar0 += xv.w * w3.z; ar1 += xv.w * w3.w;
        }
    } else {
        if (n >= N) return;
        int t = etype[n];
        const float4* wc = Wc + (size_t)t * IN_F * 8 + q;
        const float4* xp4 = (const float4*)(x + (size_t)n * IN_F);
        #pragma unroll 2
        for (int i4 = 0; i4 < IN_F / 4; ++i4) {
            float4 xv = xp4[i4];
            float4 w0 = wc[(size_t)(i4 * 4 + 0) * 8];
            float4 w1 = wc[(size_t)(i4 * 4 + 1) * 8];
            float4 w2 = wc[(size_t)(i4 * 4 + 2) * 8];
            float4 w3 = wc[(size_t)(i4 * 4 + 3) * 8];
            al0 += xv.x * w0.x; al1 += xv.x * w0.y; ar0 += xv.x * w0.z; ar1 += xv.x * w0.w;
            al0 += xv.y * w1.x; al1 += xv.y * w1.y; ar0 += xv.y * w1.z; ar1 += xv.y * w1.w;
            al0 += xv.z * w2.x; al1 += xv.z * w2.y; ar0 += xv.z * w2.z; ar1 += xv.z * w2.w;
            al0 += xv.w * w3.x; al1 += xv.w * w3.y; ar0 += xv.w * w3.z; ar1 += xv.w * w3.w;
        }
    }
    elh[(size_t)n * NH + q]     = __float2half(al0);
    elh[(size_t)n * NH + q + 8] = __float2half(al1);
    er[(size_t)n * NH + q]      = ar0;
    er[(size_t)n * NH + q + 8]  = ar1;
}

// ---------------------------------------------------------------------------
// Kernel C: scatter with per-bucket arena reservation + in-LDS sort.
// 512 blocks x 512 threads (round-14's 1000-block grid doubled the per-block
// fixed costs: 2x bin zero/scan + 780K vs 400K reservation atomics — -58us).
// NEW vs round 13: dst chunk staged in LDS (25 KB — free, only 2 blocks/CU
// at 512 blocks), eliminating the 2nd sequential dst read and turning
// pass-3's dst gathers into LDS reads (~2-way bank aliasing = free).
// ---------------------------------------------------------------------------
__global__ __launch_bounds__(512) void scatter_reserve_kernel(
        const int* __restrict__ dst,
        const int* __restrict__ src,
        int* __restrict__ cursor,        // [NB], zeroed before launch
        uint2* __restrict__ packed,      // [NB * CAPB] arenas
        int E, int NB) {
    __shared__ int dstb[SCH];              // 25.1 KB: dst chunk
    __shared__ unsigned short sidx[SCH];   // 12.5 KB
    __shared__ int hist[MAX_NB];           // counts -> reset -> running cur
    __shared__ int start_[MAX_NB];         // in-chunk exclusive starts
    __shared__ int base_[MAX_NB];          // arena reservations
    __shared__ int wsc[8];
    int tid = threadIdx.x;
    int chunk = (E + gridDim.x - 1) / gridDim.x;   // <= SCH by grid sizing
    int e0 = blockIdx.x * chunk;
    int e1 = min(E, e0 + chunk);
    int cc = e1 - e0;
    if (cc <= 0) return;

    for (int i = tid; i < MAX_NB; i += 512) hist[i] = 0;
    __syncthreads();
    // pass 1: stage dst into LDS + histogram
    for (int i = tid; i < cc; i += 512) {
        int d = dst[e0 + i];
        dstb[i] = d;
        atomicAdd(&hist[d >> NPB_SHIFT], 1);
    }
    __syncthreads();
    // reserve arena space (one returning atomic per non-empty bucket)
    for (int b = tid; b < NB; b += 512) {
        int c = hist[b];
        base_[b] = (c > 0) ? atomicAdd(&cursor[b], c) : 0;
    }
    // exclusive scan of hist[0..1023] -> start_ (2 bins/thread, 8 waves)
    int i0 = tid * 2;
    int c0 = hist[i0], c1 = hist[i0 + 1];
    int s2 = c0 + c1;
    int lane = tid & 63, wv = tid >> 6;
    int v = s2;
    #pragma unroll
    for (int off = 1; off < 64; off <<= 1) {
        int u = __shfl_up(v, (unsigned)off);
        v += (lane >= off) ? u : 0;
    }
    if (lane == 63) wsc[wv] = v;
    __syncthreads();
    int woff = 0;
    #pragma unroll
    for (int q = 0; q < 8; ++q) woff += (q < wv) ? wsc[q] : 0;
    int excl = woff + v - s2;
    start_[i0]     = excl;
    start_[i0 + 1] = excl + c0;
    // reset hist for use as running cursor
    for (int i = tid; i < MAX_NB; i += 512) hist[i] = 0;
    __syncthreads();
    // pass 2: place local index at sorted slot (dst from LDS)
    for (int i = tid; i < cc; i += 512) {
        int b = dstb[i] >> NPB_SHIFT;
        int lp = atomicAdd(&hist[b], 1);
        sidx[start_[b] + lp] = (unsigned short)i;
    }
    __syncthreads();
    // pass 3: emit in sorted order -> run-coalesced NT arena stores
    for (int i = tid; i < cc; i += 512) {
        int le = sidx[i];
        int d = dstb[le];                  // LDS gather (free vs global)
        int b = d >> NPB_SHIFT;
        int dp = base_[b] + (i - start_[b]);
        if (dp < CAPB) {  // overflow guard (P ~ 1e-20 at CAPB = mean+32sigma)
            int e = e0 + le;
            unsigned lo = ((unsigned)src[e] << NPB_SHIFT) | (unsigned)(d & (NPB - 1));
            unsigned long long v64 = ((unsigned long long)(unsigned)e << 32) |
                                     (unsigned long long)lo;
            __builtin_nontemporal_store(
                v64, (unsigned long long*)&packed[(size_t)b * CAPB + dp]);
        }
    }
}

// ---------------------------------------------------------------------------
// Kernel D: FUSED per-bucket softmax denominator + normalized output write.
//   EXACT round-13 version (measured 119 us): 2-way ILP unroll, single-wave
//   scan, NT out stores, fp16 el L2-resident. Round-14's half2 remap
//   regressed (VGPR 44, occ 33%, FETCH +88 MB) and is reverted.
// ---------------------------------------------------------------------------
__global__ __launch_bounds__(512) void bucket_sum_kernel(
        const uint2* __restrict__ packed,
        const int* __restrict__ cursor,
        const __half* __restrict__ elh,
        const float* __restrict__ er,
        float* __restrict__ out,
        int N) {
    __shared__ unsigned srt[CAP];         // 18.9 KB (src<<7 | dl)
    __shared__ int cnt0[NPB];
    __shared__ int csum[NPB];
    __shared__ int cur[NPB];
    __shared__ float erbuf[NPB * 17];     // 8.7 KB, padded
    __shared__ float invbuf[NPB * 17];    // 8.7 KB, padded
    int b = blockIdx.x;
    int base = b << NPB_SHIFT;
    size_t off = (size_t)b * CAPB;
    int tid = threadIdx.x;
    int lane = tid & 63;
    int w = tid >> 6;          // wave 0..7
    int h = lane & 15;
    int k = lane >> 4;
    int cntb = min(cursor[b], CAPB);
    int nvalid = min(NPB, N - base);

    for (int s = tid; s < nvalid * NH; s += 512) {
        int dl = s >> 4, hh = s & 15;
        erbuf[dl * 17 + hh] = er[(size_t)(base + dl) * NH + hh];
    }

    float sacc[16];
    #pragma unroll
    for (int nn = 0; nn < 16; ++nn) sacc[nn] = 0.f;

    int nchunks = (cntb + CAP - 1) / CAP;

    // ---- Phase 1: chunked counting sort + register sums ----
    for (int c = 0; c < nchunks; ++c) {
        int cbase = c * CAP;
        int cc = min(CAP, cntb - cbase);
        for (int i = tid; i < NPB; i += 512) { cnt0[i] = 0; cur[i] = 0; }
        __syncthreads();
        for (int i = tid; i < cc; i += 512)
            atomicAdd(&cnt0[packed[off + cbase + i].x & (NPB - 1)], 1);
        __syncthreads();
        // single-wave inclusive scan of 128 bins (wave 0, 2 bins/lane)
        if (w == 0) {
            int a  = cnt0[lane];
            int bb = cnt0[64 + lane];
            int va = a, vb = bb;
            #pragma unroll
            for (int offs = 1; offs < 64; offs <<= 1) {
                int ua = __shfl_up(va, (unsigned)offs);
                int ub = __shfl_up(vb, (unsigned)offs);
                va += (lane >= offs) ? ua : 0;
                vb += (lane >= offs) ? ub : 0;
            }
            int totA = __shfl(va, 63);
            csum[lane]      = va;
            csum[64 + lane] = vb + totA;
        }
        __syncthreads();
        for (int i = tid; i < cc; i += 512) {
            unsigned px = packed[off + cbase + i].x;
            int dl = (int)(px & (NPB - 1));
            int lp = atomicAdd(&cur[dl], 1);
            srt[csum[dl] - cnt0[dl] + lp] = px;
        }
        __syncthreads();
        // wave-per-node register sums, 2-way ILP unrolled
        #pragma unroll
        for (int nn = 0; nn < 16; ++nn) {
            int dl = w * 16 + nn;
            int m = cnt0[dl];        // wave-uniform
            if (m == 0) continue;
            int offL = csum[dl] - m;
            float erh = erbuf[dl * 17 + h];
            float s0 = 0.f, s1 = 0.f;
            int j = k;
            for (; j + 4 < m; j += 8) {
                unsigned p0 = srt[offL + j];
                unsigned p1 = srt[offL + j + 4];
                float v0 = __half2float(elh[(size_t)(p0 >> NPB_SHIFT) * NH + h]) + erh;
                float v1 = __half2float(elh[(size_t)(p1 >> NPB_SHIFT) * NH + h]) + erh;
                v0 = v0 > 0.f ? v0 : NEG_SLOPE * v0;
                v1 = v1 > 0.f ? v1 : NEG_SLOPE * v1;
                s0 += __expf(v0);
                s1 += __expf(v1);
            }
            if (j < m) {
                unsigned p0 = srt[offL + j];
                float v0 = __half2float(elh[(size_t)(p0 >> NPB_SHIFT) * NH + h]) + erh;
                v0 = v0 > 0.f ? v0 : NEG_SLOPE * v0;
                s0 += __expf(v0);
            }
            sacc[nn] += s0 + s1;
        }
        if (c + 1 < nchunks) __syncthreads();
    }

    #pragma unroll
    for (int nn = 0; nn < 16; ++nn) {
        int dl = w * 16 + nn;
        float s = sacc[nn];
        s += __shfl_xor(s, 16);
        s += __shfl_xor(s, 32);
        if (k == 0) invbuf[dl * 17 + h] = 1.0f / s;  // inf for deg-0: never read
    }
    __syncthreads();

    // ---- Phase 2: write normalized outputs (NT stores), 2-way unrolled ----
    int i = (tid >> 4);
    for (; i + 32 < cntb; i += 64) {
        uint2 p0 = packed[off + i];
        uint2 p1 = packed[off + i + 32];
        int dl0 = (int)(p0.x & (NPB - 1)), dl1 = (int)(p1.x & (NPB - 1));
        int sid0 = (int)(p0.x >> NPB_SHIFT), sid1 = (int)(p1.x >> NPB_SHIFT);
        float v0 = __half2float(elh[(size_t)sid0 * NH + h]) + erbuf[dl0 * 17 + h];
        float v1 = __half2float(elh[(size_t)sid1 * NH + h]) + erbuf[dl1 * 17 + h];
        v0 = v0 > 0.f ? v0 : NEG_SLOPE * v0;
        v1 = v1 > 0.f ? v1 : NEG_SLOPE * v1;
        float r0 = __expf(v0) * invbuf[dl0 * 17 + h];
        float r1 = __expf(v1) * invbuf[dl1 * 17 + h];
        __builtin_nontemporal_store(r0, &out[(size_t)p0.y * NH + h]);
        __builtin_nontemporal_store(r1, &out[(size_t)p1.y * NH + h]);
    }
    if (i < cntb) {
        uint2 p0 = packed[off + i];
        int dl0 = (int)(p0.x & (NPB - 1));
        int sid0 = (int)(p0.x >> NPB_SHIFT);
        float v0 = __half2float(elh[(size_t)sid0 * NH + h]) + erbuf[dl0 * 17 + h];
        v0 = v0 > 0.f ? v0 : NEG_SLOPE * v0;
        float r0 = __expf(v0) * invbuf[dl0 * 17 + h];
        __builtin_nontemporal_store(r0, &out[(size_t)p0.y * NH + h]);
    }
}

extern "C" void kernel_launch(void* const* d_in, const int* in_sizes, int n_in,
                              void* d_out, int out_size, void* d_ws, size_t ws_size,
                              hipStream_t stream) {
    const float* x      = (const float*)d_in[0];  // [N, 256]
    const float* W      = (const float*)d_in[1];  // [8, 256, 256]
    const float* attn_l = (const float*)d_in[2];  // [8, 16, 16]
    const float* attn_r = (const float*)d_in[3];  // [8, 16, 16]
    const int*   etype  = (const int*)d_in[4];    // [N]
    const int*   src    = (const int*)d_in[5];    // [E]
    const int*   dst    = (const int*)d_in[6];    // [E]

    int N = in_sizes[4];
    int E = in_sizes[5];
    int NB = (N + NPB - 1) >> NPB_SHIFT;  // 782 for N=100000

    float* out = (float*)d_out;  // [E, 16]

    // Workspace layout (~48 MB total, aligned chunks).
    char* ws = (char*)d_ws;
    float4* Wc     = (float4*)ws;                              // 256 KB
    __half* elh    = (__half*)(Wc + (size_t)NT * IN_F * 8);    // N*16 halfs
    float*  er     = (float*)(elh + (size_t)N * NH);           // N*16 floats
    int*    cursor = (int*)(er + (size_t)N * NH);              // MAX_NB ints
    uint2*  packed = (uint2*)(cursor + MAX_NB);                // NB*CAPB uint2

    hipMemsetAsync(cursor, 0, (size_t)NB * sizeof(int), stream);

    precompute_w_kernel<<<NT, 256, 0, stream>>>(W, attn_l, attn_r, Wc);

    int nb_proj = (N + TM - 1) / TM;
    node_proj_kernel<<<nb_proj, 256, 0, stream>>>(x, etype, Wc, elh, er, N);

    scatter_reserve_kernel<<<NBLK_S, 512, 0, stream>>>(dst, src, cursor, packed, E, NB);

    bucket_sum_kernel<<<NB, 512, 0, stream>>>(packed, cursor, elh, er, out, N);
}